// Round 10
// baseline (421.680 us; speedup 1.0000x reference)
//
#include <hip/hip_runtime.h>

typedef unsigned short u16;
typedef unsigned int u32;
typedef short bf16x8 __attribute__((ext_vector_type(8)));
typedef float f32x4 __attribute__((ext_vector_type(4)));

#define MFMA16(a, b, c) __builtin_amdgcn_mfma_f32_16x16x32_bf16((a), (b), (c), 0, 0, 0)

__device__ __forceinline__ u16 f2bf(float f) {
  u32 u = __builtin_bit_cast(u32, f);
  u += 0x7FFFu + ((u >> 16) & 1u);
  return (u16)(u >> 16);
}
// packed f32x2 -> bf16x2; HW builtin when available, software RNE otherwise
__device__ __forceinline__ u32 pk2bf(float a, float b) {
#if __has_builtin(__builtin_amdgcn_cvt_pk_bf16_f32)
  auto v = __builtin_amdgcn_cvt_pk_bf16_f32(a, b);
  return __builtin_bit_cast(u32, v);
#else
  return (u32)f2bf(a) | ((u32)f2bf(b) << 16);
#endif
}

// ws byte offsets (prep layouts identical to R8 -- verified)
#define WS_MGF   0         // bf16 [8 jt][64 lane][8 j]      B-frags of M^T   (8192 B)
#define WS_WT1F  8192      // bf16 [8 ot][2 h][4 ks][64][8]  B-frags of Wp1   (65536 B)
#define WS_WT2F  73728     // bf16 [8 mt][4 h][4 ks][64][8]  A-frags of Wp2^T (131072 B)
#define WS_B1    204800    // f32 [128]  bias1 + T0-fold
#define WS_B2    205312    // f32 [128]  bias2 + T0-fold

__global__ void prep_kernel(const float* __restrict__ adj,
                            const float* __restrict__ adj_bias,
                            const float* __restrict__ w1,
                            const float* __restrict__ b1,
                            const float* __restrict__ w2,
                            const float* __restrict__ b2,
                            char* __restrict__ ws) {
  const int tid = threadIdx.x;
  if (blockIdx.x == 0) {
    __shared__ float sa[1024], Ls[1024], L2s[1024], L3s[1024], sdre[32];
    float bias = adj_bias[0];
    for (int i = tid; i < 1024; i += 256) sa[i] = fmaxf(adj[i] + bias, 0.0f);
    __syncthreads();
    if (tid < 32) {
      float s = 0.0f;
      for (int c = 0; c < 32; ++c) s += sa[tid * 32 + c];
      sdre[tid] = 1.0f / sqrtf(s + 1e-5f);
    }
    __syncthreads();
    for (int i = tid; i < 1024; i += 256) {
      int n = i >> 5, c = i & 31;
      Ls[i] = (n == c ? 1.0f : 0.0f) - sdre[n] * sa[i] * sdre[c];
    }
    __syncthreads();
    for (int i = tid; i < 1024; i += 256) {
      int r = i >> 5, c = i & 31;
      float s = 0.0f;
      for (int m = 0; m < 32; ++m) s += Ls[r * 32 + m] * Ls[m * 32 + c];
      L2s[i] = s;
    }
    __syncthreads();
    for (int i = tid; i < 1024; i += 256) {
      int r = i >> 5, c = i & 31;
      float s = 0.0f;
      for (int m = 0; m < 32; ++m) s += L2s[r * 32 + m] * Ls[m * 32 + c];
      L3s[i] = s;
    }
    __syncthreads();
    // M stacked [128x32]: rows 0-31 I, 32-63 L, 64-95 2L^2-I, 96-127 4L^3-3L.
    // B-fragments of M^T: MGf[jt][lane][j] = M[col=jt*16+(lane&15)][k=(lane>>4)*8+j]
    u16* MGf = (u16*)(ws + WS_MGF);
    for (int i = tid; i < 4096; i += 256) {
      int jt = i >> 9, lane = (i >> 3) & 63, j = i & 7;
      int col = jt * 16 + (lane & 15);
      int k = ((lane >> 4) << 3) + j;
      int kk = col >> 5, np = col & 31;
      float v;
      if (kk == 0)      v = (np == k) ? 1.0f : 0.0f;
      else if (kk == 1) v = Ls[np * 32 + k];
      else if (kk == 2) v = 2.0f * L2s[np * 32 + k] - (np == k ? 1.0f : 0.0f);
      else              v = 4.0f * L3s[np * 32 + k] - 3.0f * Ls[np * 32 + k];
      MGf[i] = f2bf(v);
    }
    float* B1 = (float*)(ws + WS_B1);
    float* B2 = (float*)(ws + WS_B2);
    if (tid < 128) {
      float s = b1[tid];
      for (int c = 0; c < 60; ++c) s += w1[(c * 5) * 128 + tid];
      B1[tid] = s;
    } else {
      int o = tid - 128;
      float s = b2[o];
      for (int c = 0; c < 128; ++c) s += w2[(c * 5) * 128 + o];
      B2[o] = s;
    }
  } else {
    u16* WT1F = (u16*)(ws + WS_WT1F);
    u16* WT2F = (u16*)(ws + WS_WT2F);
    int g = (blockIdx.x - 1) * 256 + tid;
    // WT1F bits: j[0:3) lane[3:9) ks[9:11) h[11:12) ot[12:15)
    // element = w1 at kterm=ks, c=h*32+q*8+j (0 if c>=60), o=ot*16+(lane&15)
    for (int i = g; i < 32768; i += 16 * 256) {
      int j = i & 7, lane = (i >> 3) & 63, ks = (i >> 9) & 3;
      int h = (i >> 11) & 1, ot = i >> 12;
      int q = lane >> 4;
      int c = h * 32 + q * 8 + j;
      int o = ot * 16 + (lane & 15);
      WT1F[i] = (c < 60) ? f2bf(w1[(c * 5 + ks + 1) * 128 + o]) : (u16)0;
    }
    // WT2F bits: j[0:3) lane[3:9) ks[9:11) h[11:13) mt[13:16)
    // element = w2 at kterm=ks, c2=h*32+q*8+j, o=mt*16+(lane&15)
    for (int i = g; i < 65536; i += 16 * 256) {
      int j = i & 7, lane = (i >> 3) & 63, ks = (i >> 9) & 3;
      int h = (i >> 11) & 3, mt = i >> 13;
      int q = lane >> 4;
      int c2 = h * 32 + q * 8 + j;
      int o = mt * 16 + (lane & 15);
      WT2F[i] = f2bf(w2[(c2 * 5 + ks + 1) * 128 + o]);
    }
  }
}

// R8 structure (256 thr / 4 waves / 2 batches per block / chunked-K) with
// R9-proven ODD-dword LDS strides (conflict-free by construction):
//   Xt [64 c][42] u16  (21 dw/row; rows 60..63 zeroed; cols 0..31 used)
//   Ht [128 o][38] u16 (19 dw/row; overlays Xt region after Xt is dead)
//   Y  [32 np][138] u16 per batch (69 dw/row; kc = kterm*32 + c_local)
__global__ __launch_bounds__(256, 4) void dgcnn_kernel(
    const float* __restrict__ x,
    const char* __restrict__ ws,
    const float* __restrict__ fc_w,
    const float* __restrict__ fc_b,
    float* __restrict__ out) {
  __shared__ __align__(16) char arena[37120];
  __shared__ float red[16];
  u16* XtA = (u16*)arena;             // 5376 B
  u16* XtB = (u16*)(arena + 5376);    // 5376 B
  u16* HtA = (u16*)arena;             // 9728 B (after Xt dead)
  u16* HtB = (u16*)(arena + 9728);    // 9728 B
  u16* YA  = (u16*)(arena + 19456);   // 8832 B
  u16* YB  = (u16*)(arena + 28288);   // 8832 B

  const u16* MGf  = (const u16*)(ws + WS_MGF);
  const u16* WT1F = (const u16*)(ws + WS_WT1F);
  const u16* WT2F = (const u16*)(ws + WS_WT2F);
  const float* bias1 = (const float*)(ws + WS_B1);
  const float* bias2 = (const float*)(ws + WS_B2);

  const int tid = threadIdx.x;
  const int w = tid >> 6, lane = tid & 63;
  const int l15 = lane & 15, q = lane >> 4;
  const int b0 = blockIdx.x * 2;
  const f32x4 z4 = {0.0f, 0.0f, 0.0f, 0.0f};

  // M^T B-fragments: wave w covers M^T col tiles 2w, 2w+1 (k-term = w)
  bf16x8 mB0 = *(const bf16x8*)(MGf + ((2 * w + 0) * 64 + lane) * 8);
  bf16x8 mB1 = *(const bf16x8*)(MGf + ((2 * w + 1) * 64 + lane) * 8);

  // ---- stage x^T (both batches); rows 60..63 zeroed ----
  for (int i = tid; i < 168; i += 256) {
    int r = 60 + i / 42, c = i % 42;
    XtA[r * 42 + c] = 0;
    XtB[r * 42 + c] = 0;
  }
  const float* xb = x + (size_t)b0 * 1920;
  for (int i = tid; i < 1920; i += 256) {
    int n = i / 60, c = i - n * 60;
    u32 p = pk2bf(xb[i], xb[1920 + i]);
    XtA[c * 42 + n] = (u16)p;
    XtB[c * 42 + n] = (u16)(p >> 16);
  }
  __syncthreads();

  // ---------------- layer 1: 2 kc-chunks, acc carried in regs ----------------
  f32x4 acc1A[2][2] = {{z4, z4}, {z4, z4}};  // [nt][ot]
  f32x4 acc1B[2][2] = {{z4, z4}, {z4, z4}};
#pragma unroll
  for (int h = 0; h < 2; ++h) {
    // G1: Y[np][w*32 + c_local] = T~[kterm=w][np][c = 32h + c_local]
    {
      f32x4 gA[2][2], gB[2][2];
#pragma unroll
      for (int mtl = 0; mtl < 2; ++mtl) {
        int roff = ((2 * h + mtl) * 16 + l15) * 42 + q * 8;
        bf16x8 aA = *(const bf16x8*)&XtA[roff];
        bf16x8 aB = *(const bf16x8*)&XtB[roff];
        gA[mtl][0] = MFMA16(aA, mB0, z4);
        gA[mtl][1] = MFMA16(aA, mB1, z4);
        gB[mtl][0] = MFMA16(aB, mB0, z4);
        gB[mtl][1] = MFMA16(aB, mB1, z4);
      }
#pragma unroll
      for (int mtl = 0; mtl < 2; ++mtl)
#pragma unroll
        for (int jtl = 0; jtl < 2; ++jtl) {
          int np = jtl * 16 + l15;
          int off = np * 138 + w * 32 + mtl * 16 + q * 4;
          uint2 vA, vB;
          vA.x = pk2bf(gA[mtl][jtl][0], gA[mtl][jtl][1]);
          vA.y = pk2bf(gA[mtl][jtl][2], gA[mtl][jtl][3]);
          vB.x = pk2bf(gB[mtl][jtl][0], gB[mtl][jtl][1]);
          vB.y = pk2bf(gB[mtl][jtl][2], gB[mtl][jtl][3]);
          *(uint2*)&YA[off] = vA;
          *(uint2*)&YB[off] = vB;
        }
    }
    __syncthreads();
    // einsum1 partial over this chunk's 128 kc
#pragma unroll
    for (int ks = 0; ks < 4; ++ks) {
      bf16x8 wfa = *(const bf16x8*)(WT1F + ((((2 * w + 0) * 2 + h) * 4 + ks) * 64 + lane) * 8);
      bf16x8 wfb = *(const bf16x8*)(WT1F + ((((2 * w + 1) * 2 + h) * 4 + ks) * 64 + lane) * 8);
      int yoff = ks * 32 + q * 8;
      bf16x8 a0A = *(const bf16x8*)&YA[l15 * 138 + yoff];
      bf16x8 a1A = *(const bf16x8*)&YA[(16 + l15) * 138 + yoff];
      bf16x8 a0B = *(const bf16x8*)&YB[l15 * 138 + yoff];
      bf16x8 a1B = *(const bf16x8*)&YB[(16 + l15) * 138 + yoff];
      acc1A[0][0] = MFMA16(a0A, wfa, acc1A[0][0]);
      acc1A[0][1] = MFMA16(a0A, wfb, acc1A[0][1]);
      acc1A[1][0] = MFMA16(a1A, wfa, acc1A[1][0]);
      acc1A[1][1] = MFMA16(a1A, wfb, acc1A[1][1]);
      acc1B[0][0] = MFMA16(a0B, wfa, acc1B[0][0]);
      acc1B[0][1] = MFMA16(a0B, wfb, acc1B[0][1]);
      acc1B[1][0] = MFMA16(a1B, wfa, acc1B[1][0]);
      acc1B[1][1] = MFMA16(a1B, wfb, acc1B[1][1]);
    }
    if (h == 0) __syncthreads();  // next G1 rewrites Y
  }
  // bias+relu -> Ht (Xt dead: all Xt reads preceded the last post-G1 barrier)
#pragma unroll
  for (int ot = 0; ot < 2; ++ot) {
    int o = (2 * w + ot) * 16 + l15;
    float bv = bias1[o];
#pragma unroll
    for (int mt = 0; mt < 2; ++mt) {
      int off = o * 38 + mt * 16 + q * 4;
      uint2 vA, vB;
      vA.x = pk2bf(fmaxf(acc1A[mt][ot][0] + bv, 0.0f), fmaxf(acc1A[mt][ot][1] + bv, 0.0f));
      vA.y = pk2bf(fmaxf(acc1A[mt][ot][2] + bv, 0.0f), fmaxf(acc1A[mt][ot][3] + bv, 0.0f));
      vB.x = pk2bf(fmaxf(acc1B[mt][ot][0] + bv, 0.0f), fmaxf(acc1B[mt][ot][1] + bv, 0.0f));
      vB.y = pk2bf(fmaxf(acc1B[mt][ot][2] + bv, 0.0f), fmaxf(acc1B[mt][ot][3] + bv, 0.0f));
      *(uint2*)&HtA[off] = vA;
      *(uint2*)&HtB[off] = vB;
    }
  }
  __syncthreads();

  // ---------------- layer 2: 4 kc-chunks, acc carried in regs ----------------
  f32x4 acc2A[2][2] = {{z4, z4}, {z4, z4}};  // [ot][nt]
  f32x4 acc2B[2][2] = {{z4, z4}, {z4, z4}};
#pragma unroll
  for (int h = 0; h < 4; ++h) {
    // G1: Y[np][w*32 + c2_local] = T~2[kterm=w][np][o = 32h + c2_local]
    {
      f32x4 gA[2][2], gB[2][2];
#pragma unroll
      for (int mtl = 0; mtl < 2; ++mtl) {
        int roff = ((2 * h + mtl) * 16 + l15) * 38 + q * 8;
        bf16x8 aA = *(const bf16x8*)&HtA[roff];
        bf16x8 aB = *(const bf16x8*)&HtB[roff];
        gA[mtl][0] = MFMA16(aA, mB0, z4);
        gA[mtl][1] = MFMA16(aA, mB1, z4);
        gB[mtl][0] = MFMA16(aB, mB0, z4);
        gB[mtl][1] = MFMA16(aB, mB1, z4);
      }
#pragma unroll
      for (int mtl = 0; mtl < 2; ++mtl)
#pragma unroll
        for (int jtl = 0; jtl < 2; ++jtl) {
          int np = jtl * 16 + l15;
          int off = np * 138 + w * 32 + mtl * 16 + q * 4;
          uint2 vA, vB;
          vA.x = pk2bf(gA[mtl][jtl][0], gA[mtl][jtl][1]);
          vA.y = pk2bf(gA[mtl][jtl][2], gA[mtl][jtl][3]);
          vB.x = pk2bf(gB[mtl][jtl][0], gB[mtl][jtl][1]);
          vB.y = pk2bf(gB[mtl][jtl][2], gB[mtl][jtl][3]);
          *(uint2*)&YA[off] = vA;
          *(uint2*)&YB[off] = vB;
        }
    }
    __syncthreads();
    // einsum2 partial (flipped): D[o][n] += Wp2^T[o][chunk kc] @ Y^T[kc][n]
#pragma unroll
    for (int ks = 0; ks < 4; ++ks) {
      bf16x8 wfa = *(const bf16x8*)(WT2F + ((((2 * w + 0) * 4 + h) * 4 + ks) * 64 + lane) * 8);
      bf16x8 wfb = *(const bf16x8*)(WT2F + ((((2 * w + 1) * 4 + h) * 4 + ks) * 64 + lane) * 8);
      int yoff = ks * 32 + q * 8;
      bf16x8 by0A = *(const bf16x8*)&YA[l15 * 138 + yoff];
      bf16x8 by1A = *(const bf16x8*)&YA[(16 + l15) * 138 + yoff];
      bf16x8 by0B = *(const bf16x8*)&YB[l15 * 138 + yoff];
      bf16x8 by1B = *(const bf16x8*)&YB[(16 + l15) * 138 + yoff];
      acc2A[0][0] = MFMA16(wfa, by0A, acc2A[0][0]);
      acc2A[0][1] = MFMA16(wfa, by1A, acc2A[0][1]);
      acc2A[1][0] = MFMA16(wfb, by0A, acc2A[1][0]);
      acc2A[1][1] = MFMA16(wfb, by1A, acc2A[1][1]);
      acc2B[0][0] = MFMA16(wfa, by0B, acc2B[0][0]);
      acc2B[0][1] = MFMA16(wfa, by1B, acc2B[0][1]);
      acc2B[1][0] = MFMA16(wfb, by0B, acc2B[1][0]);
      acc2B[1][1] = MFMA16(wfb, by1B, acc2B[1][1]);
    }
    if (h < 3) __syncthreads();  // next G1 rewrites Y
  }

  // ---- epilogue: bias2+relu in regs, fc directly from accumulators ----
  float p0A = 0.0f, p1A = 0.0f, p0B = 0.0f, p1B = 0.0f;
#pragma unroll
  for (int ot = 0; ot < 2; ++ot) {
    int ob = (2 * w + ot) * 16 + q * 4;  // o base, 4 contiguous per lane
    float4 bv = *(const float4*)&bias2[ob];
#pragma unroll
    for (int nt = 0; nt < 2; ++nt) {
      int n = nt * 16 + l15;
      float4 w0 = *(const float4*)&fc_w[n * 128 + ob];
      float4 w1v = *(const float4*)&fc_w[4096 + n * 128 + ob];
      float hA0 = fmaxf(acc2A[ot][nt][0] + bv.x, 0.0f);
      float hA1 = fmaxf(acc2A[ot][nt][1] + bv.y, 0.0f);
      float hA2 = fmaxf(acc2A[ot][nt][2] + bv.z, 0.0f);
      float hA3 = fmaxf(acc2A[ot][nt][3] + bv.w, 0.0f);
      float hB0 = fmaxf(acc2B[ot][nt][0] + bv.x, 0.0f);
      float hB1 = fmaxf(acc2B[ot][nt][1] + bv.y, 0.0f);
      float hB2 = fmaxf(acc2B[ot][nt][2] + bv.z, 0.0f);
      float hB3 = fmaxf(acc2B[ot][nt][3] + bv.w, 0.0f);
      p0A = fmaf(hA0, w0.x, fmaf(hA1, w0.y, fmaf(hA2, w0.z, fmaf(hA3, w0.w, p0A))));
      p1A = fmaf(hA0, w1v.x, fmaf(hA1, w1v.y, fmaf(hA2, w1v.z, fmaf(hA3, w1v.w, p1A))));
      p0B = fmaf(hB0, w0.x, fmaf(hB1, w0.y, fmaf(hB2, w0.z, fmaf(hB3, w0.w, p0B))));
      p1B = fmaf(hB0, w1v.x, fmaf(hB1, w1v.y, fmaf(hB2, w1v.z, fmaf(hB3, w1v.w, p1B))));
    }
  }
#pragma unroll
  for (int off = 32; off >= 1; off >>= 1) {
    p0A += __shfl_xor(p0A, off);
    p1A += __shfl_xor(p1A, off);
    p0B += __shfl_xor(p0B, off);
    p1B += __shfl_xor(p1B, off);
  }
  if (lane == 0) {
    red[w * 4 + 0] = p0A;
    red[w * 4 + 1] = p1A;
    red[w * 4 + 2] = p0B;
    red[w * 4 + 3] = p1B;
  }
  __syncthreads();
  if (tid < 4) {
    float s = red[tid] + red[4 + tid] + red[8 + tid] + red[12 + tid] + fc_b[tid & 1];
    out[(b0 + (tid >> 1)) * 2 + (tid & 1)] = s;
  }
}

extern "C" void kernel_launch(void* const* d_in, const int* in_sizes, int n_in,
                              void* d_out, int out_size, void* d_ws, size_t ws_size,
                              hipStream_t stream) {
  const float* x        = (const float*)d_in[0];
  const float* adj      = (const float*)d_in[1];
  const float* adj_bias = (const float*)d_in[2];
  const float* w1       = (const float*)d_in[3];
  const float* b1       = (const float*)d_in[4];
  const float* w2       = (const float*)d_in[5];
  const float* b2       = (const float*)d_in[6];
  const float* fc_w     = (const float*)d_in[7];
  const float* fc_b     = (const float*)d_in[8];
  float* out = (float*)d_out;
  char* ws   = (char*)d_ws;

  prep_kernel<<<17, 256, 0, stream>>>(adj, adj_bias, w1, b1, w2, b2, ws);
  dgcnn_kernel<<<4096, 256, 0, stream>>>(x, ws, fc_w, fc_b, out);
}

// Round 11
// 212.953 us; speedup vs baseline: 1.9802x; 1.9802x over previous
//
#include <hip/hip_runtime.h>

typedef unsigned short u16;
typedef unsigned int u32;
typedef short bf16x8 __attribute__((ext_vector_type(8)));
typedef float f32x4 __attribute__((ext_vector_type(4)));

#define MFMA16(a, b, c) __builtin_amdgcn_mfma_f32_16x16x32_bf16((a), (b), (c), 0, 0, 0)

__device__ __forceinline__ u16 f2bf(float f) {
  u32 u = __builtin_bit_cast(u32, f);
  u += 0x7FFFu + ((u >> 16) & 1u);
  return (u16)(u >> 16);
}
// packed f32x2 -> bf16x2; HW builtin when available, software RNE otherwise
__device__ __forceinline__ u32 pk2bf(float a, float b) {
#if __has_builtin(__builtin_amdgcn_cvt_pk_bf16_f32)
  auto v = __builtin_amdgcn_cvt_pk_bf16_f32(a, b);
  return __builtin_bit_cast(u32, v);
#else
  return (u32)f2bf(a) | ((u32)f2bf(b) << 16);
#endif
}

// ws byte offsets (prep layouts identical to R8 -- verified)
#define WS_MGF   0         // bf16 [8 jt][64 lane][8 j]      B-frags of M^T   (8192 B)
#define WS_WT1F  8192      // bf16 [8 ot][2 h][4 ks][64][8]  B-frags of Wp1   (65536 B)
#define WS_WT2F  73728     // bf16 [8 mt][4 h][4 ks][64][8]  A-frags of Wp2^T (131072 B)
#define WS_B1    204800    // f32 [128]  bias1 + T0-fold
#define WS_B2    205312    // f32 [128]  bias2 + T0-fold

__global__ void prep_kernel(const float* __restrict__ adj,
                            const float* __restrict__ adj_bias,
                            const float* __restrict__ w1,
                            const float* __restrict__ b1,
                            const float* __restrict__ w2,
                            const float* __restrict__ b2,
                            char* __restrict__ ws) {
  const int tid = threadIdx.x;
  if (blockIdx.x == 0) {
    __shared__ float sa[1024], Ls[1024], L2s[1024], L3s[1024], sdre[32];
    float bias = adj_bias[0];
    for (int i = tid; i < 1024; i += 256) sa[i] = fmaxf(adj[i] + bias, 0.0f);
    __syncthreads();
    if (tid < 32) {
      float s = 0.0f;
      for (int c = 0; c < 32; ++c) s += sa[tid * 32 + c];
      sdre[tid] = 1.0f / sqrtf(s + 1e-5f);
    }
    __syncthreads();
    for (int i = tid; i < 1024; i += 256) {
      int n = i >> 5, c = i & 31;
      Ls[i] = (n == c ? 1.0f : 0.0f) - sdre[n] * sa[i] * sdre[c];
    }
    __syncthreads();
    for (int i = tid; i < 1024; i += 256) {
      int r = i >> 5, c = i & 31;
      float s = 0.0f;
      for (int m = 0; m < 32; ++m) s += Ls[r * 32 + m] * Ls[m * 32 + c];
      L2s[i] = s;
    }
    __syncthreads();
    for (int i = tid; i < 1024; i += 256) {
      int r = i >> 5, c = i & 31;
      float s = 0.0f;
      for (int m = 0; m < 32; ++m) s += L2s[r * 32 + m] * Ls[m * 32 + c];
      L3s[i] = s;
    }
    __syncthreads();
    // M stacked [128x32]: rows 0-31 I, 32-63 L, 64-95 2L^2-I, 96-127 4L^3-3L.
    // B-fragments of M^T: MGf[jt][lane][j] = M[col=jt*16+(lane&15)][k=(lane>>4)*8+j]
    u16* MGf = (u16*)(ws + WS_MGF);
    for (int i = tid; i < 4096; i += 256) {
      int jt = i >> 9, lane = (i >> 3) & 63, j = i & 7;
      int col = jt * 16 + (lane & 15);
      int k = ((lane >> 4) << 3) + j;
      int kk = col >> 5, np = col & 31;
      float v;
      if (kk == 0)      v = (np == k) ? 1.0f : 0.0f;
      else if (kk == 1) v = Ls[np * 32 + k];
      else if (kk == 2) v = 2.0f * L2s[np * 32 + k] - (np == k ? 1.0f : 0.0f);
      else              v = 4.0f * L3s[np * 32 + k] - 3.0f * Ls[np * 32 + k];
      MGf[i] = f2bf(v);
    }
    float* B1 = (float*)(ws + WS_B1);
    float* B2 = (float*)(ws + WS_B2);
    if (tid < 128) {
      float s = b1[tid];
      for (int c = 0; c < 60; ++c) s += w1[(c * 5) * 128 + tid];
      B1[tid] = s;
    } else {
      int o = tid - 128;
      float s = b2[o];
      for (int c = 0; c < 128; ++c) s += w2[(c * 5) * 128 + o];
      B2[o] = s;
    }
  } else {
    u16* WT1F = (u16*)(ws + WS_WT1F);
    u16* WT2F = (u16*)(ws + WS_WT2F);
    int g = (blockIdx.x - 1) * 256 + tid;
    // WT1F bits: j[0:3) lane[3:9) ks[9:11) h[11:12) ot[12:15)
    // element = w1 at kterm=ks, c=h*32+q*8+j (0 if c>=60), o=ot*16+(lane&15)
    for (int i = g; i < 32768; i += 16 * 256) {
      int j = i & 7, lane = (i >> 3) & 63, ks = (i >> 9) & 3;
      int h = (i >> 11) & 1, ot = i >> 12;
      int q = lane >> 4;
      int c = h * 32 + q * 8 + j;
      int o = ot * 16 + (lane & 15);
      WT1F[i] = (c < 60) ? f2bf(w1[(c * 5 + ks + 1) * 128 + o]) : (u16)0;
    }
    // WT2F bits: j[0:3) lane[3:9) ks[9:11) h[11:13) mt[13:16)
    // element = w2 at kterm=ks, c2=h*32+q*8+j, o=mt*16+(lane&15)
    for (int i = g; i < 65536; i += 16 * 256) {
      int j = i & 7, lane = (i >> 3) & 63, ks = (i >> 9) & 3;
      int h = (i >> 11) & 3, mt = i >> 13;
      int q = lane >> 4;
      int c2 = h * 32 + q * 8 + j;
      int o = mt * 16 + (lane & 15);
      WT2F[i] = f2bf(w2[(c2 * 5 + ks + 1) * 128 + o]);
    }
  }
}

// R8 structure (256 thr / 4 waves / 2 batches / chunked-K / R8 aligned strides)
// + wave-batch specialization: waves 0,1 -> batch A; waves 2,3 -> batch B.
// Sub-wave s handles G1 kterms {2s,2s+1} and einsum o-tiles {4s..4s+3}.
// LDS (16B-aligned strides -- R10 proved odd strides catastrophic):
//   Xt [64 c][40] u16, Ht [128 o][36] u16 (overlays Xt), Y [32 np][136] u16/batch
__global__ __launch_bounds__(256, 4) void dgcnn_kernel(
    const float* __restrict__ x,
    const char* __restrict__ ws,
    const float* __restrict__ fc_w,
    const float* __restrict__ fc_b,
    float* __restrict__ out) {
  __shared__ __align__(16) char arena[35840];
  __shared__ float red[8];
  u16* XtA = (u16*)arena;             // 5120 B
  u16* XtB = (u16*)(arena + 5120);    // 5120 B
  u16* HtA = (u16*)arena;             // 9216 B (after Xt dead)
  u16* HtB = (u16*)(arena + 9216);    // 9216 B
  u16* YA  = (u16*)(arena + 18432);   // 8704 B
  u16* YB  = (u16*)(arena + 27136);   // 8704 B

  const u16* MGf  = (const u16*)(ws + WS_MGF);
  const u16* WT1F = (const u16*)(ws + WS_WT1F);
  const u16* WT2F = (const u16*)(ws + WS_WT2F);
  const float* bias1 = (const float*)(ws + WS_B1);
  const float* bias2 = (const float*)(ws + WS_B2);

  const int tid = threadIdx.x;
  const int w = tid >> 6, lane = tid & 63;
  const int s = w & 1;        // sub-wave within batch pair
  const int bsel = w >> 1;    // 0 -> batch A, 1 -> batch B
  const int l15 = lane & 15, q = lane >> 4;
  const int b0 = blockIdx.x * 2;
  const f32x4 z4 = {0.0f, 0.0f, 0.0f, 0.0f};

  u16* Xtw = bsel ? XtB : XtA;
  u16* Htw = bsel ? HtB : HtA;
  u16* Yw  = bsel ? YB : YA;

  // M^T B-fragments: sub-wave s covers kterms 2s,2s+1 -> col tiles jt = 4s+t
  bf16x8 mB[4];
#pragma unroll
  for (int t = 0; t < 4; ++t)
    mB[t] = *(const bf16x8*)(MGf + ((4 * s + t) * 64 + lane) * 8);

  // ---- stage x^T (both batches, all threads); rows 60..63 zeroed ----
  for (int i = tid; i < 160; i += 256) {
    int r = 60 + i / 40, c = i % 40;
    XtA[r * 40 + c] = 0;
    XtB[r * 40 + c] = 0;
  }
  const float* xb = x + (size_t)b0 * 1920;
  for (int i = tid; i < 1920; i += 256) {
    int n = i / 60, c = i - n * 60;
    u32 p = pk2bf(xb[i], xb[1920 + i]);
    XtA[c * 40 + n] = (u16)p;
    XtB[c * 40 + n] = (u16)(p >> 16);
  }
  __syncthreads();

  // ---------------- layer 1: 2 kc-chunks, acc carried in regs ----------------
  f32x4 acc1[4][2] = {{z4, z4}, {z4, z4}, {z4, z4}, {z4, z4}};  // [otl][nt]
#pragma unroll
  for (int h = 0; h < 2; ++h) {
    // G1: Yw[np][(2s+ktl)*32 + c_local] = T~[kterm][np][c = 32h + c_local]
    {
      bf16x8 aX0 = *(const bf16x8*)&Xtw[((2 * h + 0) * 16 + l15) * 40 + q * 8];
      bf16x8 aX1 = *(const bf16x8*)&Xtw[((2 * h + 1) * 16 + l15) * 40 + q * 8];
#pragma unroll
      for (int ktl = 0; ktl < 2; ++ktl) {
        f32x4 g00 = MFMA16(aX0, mB[2 * ktl + 0], z4);  // mtl=0, jtl=0
        f32x4 g01 = MFMA16(aX0, mB[2 * ktl + 1], z4);  // mtl=0, jtl=1
        f32x4 g10 = MFMA16(aX1, mB[2 * ktl + 0], z4);  // mtl=1, jtl=0
        f32x4 g11 = MFMA16(aX1, mB[2 * ktl + 1], z4);  // mtl=1, jtl=1
        int cb = (2 * s + ktl) * 32 + q * 4;
        uint2 v;
        v.x = pk2bf(g00[0], g00[1]); v.y = pk2bf(g00[2], g00[3]);
        *(uint2*)&Yw[l15 * 136 + cb] = v;
        v.x = pk2bf(g01[0], g01[1]); v.y = pk2bf(g01[2], g01[3]);
        *(uint2*)&Yw[(16 + l15) * 136 + cb] = v;
        v.x = pk2bf(g10[0], g10[1]); v.y = pk2bf(g10[2], g10[3]);
        *(uint2*)&Yw[l15 * 136 + cb + 16] = v;
        v.x = pk2bf(g11[0], g11[1]); v.y = pk2bf(g11[2], g11[3]);
        *(uint2*)&Yw[(16 + l15) * 136 + cb + 16] = v;
      }
    }
    __syncthreads();
    // einsum1 partial over this chunk's 128 kc (own batch only, 4 o-tiles)
#pragma unroll
    for (int ks = 0; ks < 4; ++ks) {
      int yoff = ks * 32 + q * 8;
      bf16x8 a0 = *(const bf16x8*)&Yw[l15 * 136 + yoff];
      bf16x8 a1 = *(const bf16x8*)&Yw[(16 + l15) * 136 + yoff];
#pragma unroll
      for (int otl = 0; otl < 4; ++otl) {
        bf16x8 wf = *(const bf16x8*)(WT1F + ((((4 * s + otl) * 2 + h) * 4 + ks) * 64 + lane) * 8);
        acc1[otl][0] = MFMA16(a0, wf, acc1[otl][0]);
        acc1[otl][1] = MFMA16(a1, wf, acc1[otl][1]);
      }
    }
    if (h == 0) __syncthreads();  // next G1 rewrites Y
  }
  // bias+relu -> Htw (Xt dead: all Xt reads preceded the last post-G1 barrier)
#pragma unroll
  for (int otl = 0; otl < 4; ++otl) {
    int o = (4 * s + otl) * 16 + l15;
    float bv = bias1[o];
#pragma unroll
    for (int nt = 0; nt < 2; ++nt) {
      uint2 v;
      v.x = pk2bf(fmaxf(acc1[otl][nt][0] + bv, 0.0f), fmaxf(acc1[otl][nt][1] + bv, 0.0f));
      v.y = pk2bf(fmaxf(acc1[otl][nt][2] + bv, 0.0f), fmaxf(acc1[otl][nt][3] + bv, 0.0f));
      *(uint2*)&Htw[o * 36 + nt * 16 + q * 4] = v;
    }
  }
  __syncthreads();

  // ---------------- layer 2: 4 kc-chunks, acc carried in regs ----------------
  f32x4 acc2[4][2] = {{z4, z4}, {z4, z4}, {z4, z4}, {z4, z4}};  // [otl][nt]
#pragma unroll
  for (int h = 0; h < 4; ++h) {
    // G1: Yw[np][(2s+ktl)*32 + c2_local] = T~2[kterm][np][o2 = 32h + c2_local]
    {
      bf16x8 aH0 = *(const bf16x8*)&Htw[((2 * h + 0) * 16 + l15) * 36 + q * 8];
      bf16x8 aH1 = *(const bf16x8*)&Htw[((2 * h + 1) * 16 + l15) * 36 + q * 8];
#pragma unroll
      for (int ktl = 0; ktl < 2; ++ktl) {
        f32x4 g00 = MFMA16(aH0, mB[2 * ktl + 0], z4);
        f32x4 g01 = MFMA16(aH0, mB[2 * ktl + 1], z4);
        f32x4 g10 = MFMA16(aH1, mB[2 * ktl + 0], z4);
        f32x4 g11 = MFMA16(aH1, mB[2 * ktl + 1], z4);
        int cb = (2 * s + ktl) * 32 + q * 4;
        uint2 v;
        v.x = pk2bf(g00[0], g00[1]); v.y = pk2bf(g00[2], g00[3]);
        *(uint2*)&Yw[l15 * 136 + cb] = v;
        v.x = pk2bf(g01[0], g01[1]); v.y = pk2bf(g01[2], g01[3]);
        *(uint2*)&Yw[(16 + l15) * 136 + cb] = v;
        v.x = pk2bf(g10[0], g10[1]); v.y = pk2bf(g10[2], g10[3]);
        *(uint2*)&Yw[l15 * 136 + cb + 16] = v;
        v.x = pk2bf(g11[0], g11[1]); v.y = pk2bf(g11[2], g11[3]);
        *(uint2*)&Yw[(16 + l15) * 136 + cb + 16] = v;
      }
    }
    __syncthreads();
    // einsum2 partial (flipped): D[o][n] += Wp2^T[o][chunk kc] @ Y^T[kc][n]
#pragma unroll
    for (int ks = 0; ks < 4; ++ks) {
      int yoff = ks * 32 + q * 8;
      bf16x8 by0 = *(const bf16x8*)&Yw[l15 * 136 + yoff];
      bf16x8 by1 = *(const bf16x8*)&Yw[(16 + l15) * 136 + yoff];
#pragma unroll
      for (int otl = 0; otl < 4; ++otl) {
        bf16x8 aw = *(const bf16x8*)(WT2F + ((((4 * s + otl) * 4 + h) * 4 + ks) * 64 + lane) * 8);
        acc2[otl][0] = MFMA16(aw, by0, acc2[otl][0]);
        acc2[otl][1] = MFMA16(aw, by1, acc2[otl][1]);
      }
    }
    if (h < 3) __syncthreads();  // next G1 rewrites Y
  }

  // ---- epilogue: bias2+relu in regs, fc directly from accumulators ----
  float p0 = 0.0f, p1 = 0.0f;
#pragma unroll
  for (int otl = 0; otl < 4; ++otl) {
    int ob = (4 * s + otl) * 16 + q * 4;  // o base, 4 contiguous per lane
    float4 bv = *(const float4*)&bias2[ob];
#pragma unroll
    for (int nt = 0; nt < 2; ++nt) {
      int n = nt * 16 + l15;
      float4 w0 = *(const float4*)&fc_w[n * 128 + ob];
      float4 w1v = *(const float4*)&fc_w[4096 + n * 128 + ob];
      float h0 = fmaxf(acc2[otl][nt][0] + bv.x, 0.0f);
      float h1 = fmaxf(acc2[otl][nt][1] + bv.y, 0.0f);
      float h2 = fmaxf(acc2[otl][nt][2] + bv.z, 0.0f);
      float h3 = fmaxf(acc2[otl][nt][3] + bv.w, 0.0f);
      p0 = fmaf(h0, w0.x, fmaf(h1, w0.y, fmaf(h2, w0.z, fmaf(h3, w0.w, p0))));
      p1 = fmaf(h0, w1v.x, fmaf(h1, w1v.y, fmaf(h2, w1v.z, fmaf(h3, w1v.w, p1))));
    }
  }
#pragma unroll
  for (int off = 32; off >= 1; off >>= 1) {
    p0 += __shfl_xor(p0, off);
    p1 += __shfl_xor(p1, off);
  }
  if (lane == 0) {
    red[w * 2 + 0] = p0;
    red[w * 2 + 1] = p1;
  }
  __syncthreads();
  if (tid < 4) {
    int j = tid & 1, bb = tid >> 1;
    out[(b0 + bb) * 2 + j] = red[bb * 4 + j] + red[bb * 4 + 2 + j] + fc_b[j];
  }
}

extern "C" void kernel_launch(void* const* d_in, const int* in_sizes, int n_in,
                              void* d_out, int out_size, void* d_ws, size_t ws_size,
                              hipStream_t stream) {
  const float* x        = (const float*)d_in[0];
  const float* adj      = (const float*)d_in[1];
  const float* adj_bias = (const float*)d_in[2];
  const float* w1       = (const float*)d_in[3];
  const float* b1       = (const float*)d_in[4];
  const float* w2       = (const float*)d_in[5];
  const float* b2       = (const float*)d_in[6];
  const float* fc_w     = (const float*)d_in[7];
  const float* fc_b     = (const float*)d_in[8];
  float* out = (float*)d_out;
  char* ws   = (char*)d_ws;

  prep_kernel<<<17, 256, 0, stream>>>(adj, adj_bias, w1, b1, w2, b2, ws);
  dgcnn_kernel<<<4096, 256, 0, stream>>>(x, ws, fc_w, fc_b, out);
}

// Round 12
// 207.473 us; speedup vs baseline: 2.0325x; 1.0264x over previous
//
#include <hip/hip_runtime.h>

typedef unsigned short u16;
typedef unsigned int u32;
typedef short bf16x8 __attribute__((ext_vector_type(8)));
typedef float f32x4 __attribute__((ext_vector_type(4)));

#define MFMA16(a, b, c) __builtin_amdgcn_mfma_f32_16x16x32_bf16((a), (b), (c), 0, 0, 0)

__device__ __forceinline__ u16 f2bf(float f) {
  u32 u = __builtin_bit_cast(u32, f);
  u += 0x7FFFu + ((u >> 16) & 1u);
  return (u16)(u >> 16);
}
// packed f32x2 -> bf16x2; HW builtin when available, software RNE otherwise
__device__ __forceinline__ u32 pk2bf(float a, float b) {
#if __has_builtin(__builtin_amdgcn_cvt_pk_bf16_f32)
  auto v = __builtin_amdgcn_cvt_pk_bf16_f32(a, b);
  return __builtin_bit_cast(u32, v);
#else
  return (u32)f2bf(a) | ((u32)f2bf(b) << 16);
#endif
}

// ws byte offsets (prep layouts identical to R8 -- verified)
#define WS_MGF   0         // bf16 [8 jt][64 lane][8 j]      B-frags of M^T   (8192 B)
#define WS_WT1F  8192      // bf16 [8 ot][2 h][4 ks][64][8]  B-frags of Wp1   (65536 B)
#define WS_WT2F  73728     // bf16 [8 mt][4 h][4 ks][64][8]  A-frags of Wp2^T (131072 B)
#define WS_B1    204800    // f32 [128]  bias1 + T0-fold
#define WS_B2    205312    // f32 [128]  bias2 + T0-fold

__global__ void prep_kernel(const float* __restrict__ adj,
                            const float* __restrict__ adj_bias,
                            const float* __restrict__ w1,
                            const float* __restrict__ b1,
                            const float* __restrict__ w2,
                            const float* __restrict__ b2,
                            char* __restrict__ ws) {
  const int tid = threadIdx.x;
  if (blockIdx.x == 0) {
    __shared__ float sa[1024], Ls[1024], L2s[1024], L3s[1024], sdre[32];
    float bias = adj_bias[0];
    for (int i = tid; i < 1024; i += 256) sa[i] = fmaxf(adj[i] + bias, 0.0f);
    __syncthreads();
    if (tid < 32) {
      float s = 0.0f;
      for (int c = 0; c < 32; ++c) s += sa[tid * 32 + c];
      sdre[tid] = 1.0f / sqrtf(s + 1e-5f);
    }
    __syncthreads();
    for (int i = tid; i < 1024; i += 256) {
      int n = i >> 5, c = i & 31;
      Ls[i] = (n == c ? 1.0f : 0.0f) - sdre[n] * sa[i] * sdre[c];
    }
    __syncthreads();
    for (int i = tid; i < 1024; i += 256) {
      int r = i >> 5, c = i & 31;
      float s = 0.0f;
      for (int m = 0; m < 32; ++m) s += Ls[r * 32 + m] * Ls[m * 32 + c];
      L2s[i] = s;
    }
    __syncthreads();
    for (int i = tid; i < 1024; i += 256) {
      int r = i >> 5, c = i & 31;
      float s = 0.0f;
      for (int m = 0; m < 32; ++m) s += L2s[r * 32 + m] * Ls[m * 32 + c];
      L3s[i] = s;
    }
    __syncthreads();
    // M stacked [128x32]: rows 0-31 I, 32-63 L, 64-95 2L^2-I, 96-127 4L^3-3L.
    // B-fragments of M^T: MGf[jt][lane][j] = M[col=jt*16+(lane&15)][k=(lane>>4)*8+j]
    u16* MGf = (u16*)(ws + WS_MGF);
    for (int i = tid; i < 4096; i += 256) {
      int jt = i >> 9, lane = (i >> 3) & 63, j = i & 7;
      int col = jt * 16 + (lane & 15);
      int k = ((lane >> 4) << 3) + j;
      int kk = col >> 5, np = col & 31;
      float v;
      if (kk == 0)      v = (np == k) ? 1.0f : 0.0f;
      else if (kk == 1) v = Ls[np * 32 + k];
      else if (kk == 2) v = 2.0f * L2s[np * 32 + k] - (np == k ? 1.0f : 0.0f);
      else              v = 4.0f * L3s[np * 32 + k] - 3.0f * Ls[np * 32 + k];
      MGf[i] = f2bf(v);
    }
    float* B1 = (float*)(ws + WS_B1);
    float* B2 = (float*)(ws + WS_B2);
    if (tid < 128) {
      float s = b1[tid];
      for (int c = 0; c < 60; ++c) s += w1[(c * 5) * 128 + tid];
      B1[tid] = s;
    } else {
      int o = tid - 128;
      float s = b2[o];
      for (int c = 0; c < 128; ++c) s += w2[(c * 5) * 128 + o];
      B2[o] = s;
    }
  } else {
    u16* WT1F = (u16*)(ws + WS_WT1F);
    u16* WT2F = (u16*)(ws + WS_WT2F);
    int g = (blockIdx.x - 1) * 256 + tid;
    // WT1F bits: j[0:3) lane[3:9) ks[9:11) h[11:12) ot[12:15)
    // element = w1 at kterm=ks, c=h*32+q*8+j (0 if c>=60), o=ot*16+(lane&15)
    for (int i = g; i < 32768; i += 16 * 256) {
      int j = i & 7, lane = (i >> 3) & 63, ks = (i >> 9) & 3;
      int h = (i >> 11) & 1, ot = i >> 12;
      int q = lane >> 4;
      int c = h * 32 + q * 8 + j;
      int o = ot * 16 + (lane & 15);
      WT1F[i] = (c < 60) ? f2bf(w1[(c * 5 + ks + 1) * 128 + o]) : (u16)0;
    }
    // WT2F bits: j[0:3) lane[3:9) ks[9:11) h[11:13) mt[13:16)
    // element = w2 at kterm=ks, c2=h*32+q*8+j, o=mt*16+(lane&15)
    for (int i = g; i < 65536; i += 16 * 256) {
      int j = i & 7, lane = (i >> 3) & 63, ks = (i >> 9) & 3;
      int h = (i >> 11) & 3, mt = i >> 13;
      int q = lane >> 4;
      int c2 = h * 32 + q * 8 + j;
      int o = mt * 16 + (lane & 15);
      WT2F[i] = f2bf(w2[(c2 * 5 + ks + 1) * 128 + o]);
    }
  }
}

// R8 structure (256 thr / 4 waves / 2 batches / chunked-K / aligned strides
// 40/36/136) + Y DOUBLE-BUFFER software pipeline: merged phases
// {einsum(h) || G1(h+1)} share one barrier, so G1's MFMAs overlap einsum's
// weight-load latency and barrier count drops (L2: 7 -> 4).
__global__ __launch_bounds__(256, 3) void dgcnn_kernel(
    const float* __restrict__ x,
    const char* __restrict__ ws,
    const float* __restrict__ fc_w,
    const float* __restrict__ fc_b,
    float* __restrict__ out) {
  __shared__ __align__(16) char arena[53248];
  __shared__ float red[16];
  u16* XtA = (u16*)arena;             // 5120 B
  u16* XtB = (u16*)(arena + 5120);    // 5120 B
  u16* HtA = (u16*)arena;             // 9216 B (after Xt dead)
  u16* HtB = (u16*)(arena + 9216);    // 9216 B
  u16* Y0A = (u16*)(arena + 18432);   // 8704 B  chunk-buffer 0
  u16* Y0B = (u16*)(arena + 27136);   // 8704 B
  u16* Y1A = (u16*)(arena + 35840);   // 8704 B  chunk-buffer 1
  u16* Y1B = (u16*)(arena + 44544);   // 8704 B

  const u16* MGf  = (const u16*)(ws + WS_MGF);
  const u16* WT1F = (const u16*)(ws + WS_WT1F);
  const u16* WT2F = (const u16*)(ws + WS_WT2F);
  const float* bias1 = (const float*)(ws + WS_B1);
  const float* bias2 = (const float*)(ws + WS_B2);

  const int tid = threadIdx.x;
  const int w = tid >> 6, lane = tid & 63;
  const int l15 = lane & 15, q = lane >> 4;
  const int b0 = blockIdx.x * 2;
  const f32x4 z4 = {0.0f, 0.0f, 0.0f, 0.0f};

  // M^T B-fragments: wave w covers M^T col tiles 2w, 2w+1 (k-term = w)
  bf16x8 mB0 = *(const bf16x8*)(MGf + ((2 * w + 0) * 64 + lane) * 8);
  bf16x8 mB1 = *(const bf16x8*)(MGf + ((2 * w + 1) * 64 + lane) * 8);

  // ---- stage x^T (both batches); rows 60..63 zeroed ----
  for (int i = tid; i < 160; i += 256) {
    int r = 60 + i / 40, c = i % 40;
    XtA[r * 40 + c] = 0;
    XtB[r * 40 + c] = 0;
  }
  const float* xb = x + (size_t)b0 * 1920;
  for (int i = tid; i < 1920; i += 256) {
    int n = i / 60, c = i - n * 60;
    u32 p = pk2bf(xb[i], xb[1920 + i]);
    XtA[c * 40 + n] = (u16)p;
    XtB[c * 40 + n] = (u16)(p >> 16);
  }

  f32x4 acc1A[2][2] = {{z4, z4}, {z4, z4}};  // [nt][ot]
  f32x4 acc1B[2][2] = {{z4, z4}, {z4, z4}};

  // G1 layer1 for chunk h into (Ya, Yb)
  auto G1L1 = [&](int h, u16* Ya, u16* Yb) {
    f32x4 gA[2][2], gB[2][2];
#pragma unroll
    for (int mtl = 0; mtl < 2; ++mtl) {
      int roff = ((2 * h + mtl) * 16 + l15) * 40 + q * 8;
      bf16x8 aA = *(const bf16x8*)&XtA[roff];
      bf16x8 aB = *(const bf16x8*)&XtB[roff];
      gA[mtl][0] = MFMA16(aA, mB0, z4);
      gA[mtl][1] = MFMA16(aA, mB1, z4);
      gB[mtl][0] = MFMA16(aB, mB0, z4);
      gB[mtl][1] = MFMA16(aB, mB1, z4);
    }
#pragma unroll
    for (int mtl = 0; mtl < 2; ++mtl)
#pragma unroll
      for (int jtl = 0; jtl < 2; ++jtl) {
        int np = jtl * 16 + l15;
        int off = np * 136 + w * 32 + mtl * 16 + q * 4;
        uint2 vA, vB;
        vA.x = pk2bf(gA[mtl][jtl][0], gA[mtl][jtl][1]);
        vA.y = pk2bf(gA[mtl][jtl][2], gA[mtl][jtl][3]);
        vB.x = pk2bf(gB[mtl][jtl][0], gB[mtl][jtl][1]);
        vB.y = pk2bf(gB[mtl][jtl][2], gB[mtl][jtl][3]);
        *(uint2*)&Ya[off] = vA;
        *(uint2*)&Yb[off] = vB;
      }
  };
  // einsum1 partial for chunk h from (Ya, Yb)
  auto E1 = [&](int h, const u16* Ya, const u16* Yb) {
#pragma unroll
    for (int ks = 0; ks < 4; ++ks) {
      bf16x8 wfa = *(const bf16x8*)(WT1F + ((((2 * w + 0) * 2 + h) * 4 + ks) * 64 + lane) * 8);
      bf16x8 wfb = *(const bf16x8*)(WT1F + ((((2 * w + 1) * 2 + h) * 4 + ks) * 64 + lane) * 8);
      int yoff = ks * 32 + q * 8;
      bf16x8 a0A = *(const bf16x8*)&Ya[l15 * 136 + yoff];
      bf16x8 a1A = *(const bf16x8*)&Ya[(16 + l15) * 136 + yoff];
      bf16x8 a0B = *(const bf16x8*)&Yb[l15 * 136 + yoff];
      bf16x8 a1B = *(const bf16x8*)&Yb[(16 + l15) * 136 + yoff];
      acc1A[0][0] = MFMA16(a0A, wfa, acc1A[0][0]);
      acc1A[0][1] = MFMA16(a0A, wfb, acc1A[0][1]);
      acc1A[1][0] = MFMA16(a1A, wfa, acc1A[1][0]);
      acc1A[1][1] = MFMA16(a1A, wfb, acc1A[1][1]);
      acc1B[0][0] = MFMA16(a0B, wfa, acc1B[0][0]);
      acc1B[0][1] = MFMA16(a0B, wfb, acc1B[0][1]);
      acc1B[1][0] = MFMA16(a1B, wfa, acc1B[1][0]);
      acc1B[1][1] = MFMA16(a1B, wfb, acc1B[1][1]);
    }
  };

  // ---- layer 1 pipeline: G1(0) | bar | G1(1)+E1(0) | bar | E1(1)+bias ----
  __syncthreads();        // staging complete
  G1L1(0, Y0A, Y0B);
  __syncthreads();
  G1L1(1, Y1A, Y1B);
  E1(0, Y0A, Y0B);
  __syncthreads();
  E1(1, Y1A, Y1B);
  // bias+relu -> Ht (Xt dead: last Xt reads were in G1L1(1), pre-barrier)
#pragma unroll
  for (int ot = 0; ot < 2; ++ot) {
    int o = (2 * w + ot) * 16 + l15;
    float bv = bias1[o];
#pragma unroll
    for (int mt = 0; mt < 2; ++mt) {
      int off = o * 36 + mt * 16 + q * 4;
      uint2 vA, vB;
      vA.x = pk2bf(fmaxf(acc1A[mt][ot][0] + bv, 0.0f), fmaxf(acc1A[mt][ot][1] + bv, 0.0f));
      vA.y = pk2bf(fmaxf(acc1A[mt][ot][2] + bv, 0.0f), fmaxf(acc1A[mt][ot][3] + bv, 0.0f));
      vB.x = pk2bf(fmaxf(acc1B[mt][ot][0] + bv, 0.0f), fmaxf(acc1B[mt][ot][1] + bv, 0.0f));
      vB.y = pk2bf(fmaxf(acc1B[mt][ot][2] + bv, 0.0f), fmaxf(acc1B[mt][ot][3] + bv, 0.0f));
      *(uint2*)&HtA[off] = vA;
      *(uint2*)&HtB[off] = vB;
    }
  }
  __syncthreads();

  // ---------------- layer 2: 4 chunks, double-buffered pipeline ----------------
  f32x4 acc2A[2][2] = {{z4, z4}, {z4, z4}};  // [ot][nt]
  f32x4 acc2B[2][2] = {{z4, z4}, {z4, z4}};

  auto G1L2 = [&](int h, u16* Ya, u16* Yb) {
    f32x4 gA[2][2], gB[2][2];
#pragma unroll
    for (int mtl = 0; mtl < 2; ++mtl) {
      int roff = ((2 * h + mtl) * 16 + l15) * 36 + q * 8;
      bf16x8 aA = *(const bf16x8*)&HtA[roff];
      bf16x8 aB = *(const bf16x8*)&HtB[roff];
      gA[mtl][0] = MFMA16(aA, mB0, z4);
      gA[mtl][1] = MFMA16(aA, mB1, z4);
      gB[mtl][0] = MFMA16(aB, mB0, z4);
      gB[mtl][1] = MFMA16(aB, mB1, z4);
    }
#pragma unroll
    for (int mtl = 0; mtl < 2; ++mtl)
#pragma unroll
      for (int jtl = 0; jtl < 2; ++jtl) {
        int np = jtl * 16 + l15;
        int off = np * 136 + w * 32 + mtl * 16 + q * 4;
        uint2 vA, vB;
        vA.x = pk2bf(gA[mtl][jtl][0], gA[mtl][jtl][1]);
        vA.y = pk2bf(gA[mtl][jtl][2], gA[mtl][jtl][3]);
        vB.x = pk2bf(gB[mtl][jtl][0], gB[mtl][jtl][1]);
        vB.y = pk2bf(gB[mtl][jtl][2], gB[mtl][jtl][3]);
        *(uint2*)&Ya[off] = vA;
        *(uint2*)&Yb[off] = vB;
      }
  };
  auto E2 = [&](int h, const u16* Ya, const u16* Yb) {
#pragma unroll
    for (int ks = 0; ks < 4; ++ks) {
      bf16x8 wfa = *(const bf16x8*)(WT2F + ((((2 * w + 0) * 4 + h) * 4 + ks) * 64 + lane) * 8);
      bf16x8 wfb = *(const bf16x8*)(WT2F + ((((2 * w + 1) * 4 + h) * 4 + ks) * 64 + lane) * 8);
      int yoff = ks * 32 + q * 8;
      bf16x8 by0A = *(const bf16x8*)&Ya[l15 * 136 + yoff];
      bf16x8 by1A = *(const bf16x8*)&Ya[(16 + l15) * 136 + yoff];
      bf16x8 by0B = *(const bf16x8*)&Yb[l15 * 136 + yoff];
      bf16x8 by1B = *(const bf16x8*)&Yb[(16 + l15) * 136 + yoff];
      acc2A[0][0] = MFMA16(wfa, by0A, acc2A[0][0]);
      acc2A[0][1] = MFMA16(wfa, by1A, acc2A[0][1]);
      acc2A[1][0] = MFMA16(wfb, by0A, acc2A[1][0]);
      acc2A[1][1] = MFMA16(wfb, by1A, acc2A[1][1]);
      acc2B[0][0] = MFMA16(wfa, by0B, acc2B[0][0]);
      acc2B[0][1] = MFMA16(wfa, by1B, acc2B[0][1]);
      acc2B[1][0] = MFMA16(wfb, by0B, acc2B[1][0]);
      acc2B[1][1] = MFMA16(wfb, by1B, acc2B[1][1]);
    }
  };

  // G1(0) | bar | G1(1)+E2(0) | bar | G1(2)+E2(1) | bar | G1(3)+E2(2) | bar | E2(3)
  G1L2(0, Y0A, Y0B);
  __syncthreads();
  G1L2(1, Y1A, Y1B);
  E2(0, Y0A, Y0B);
  __syncthreads();
  G1L2(2, Y0A, Y0B);
  E2(1, Y1A, Y1B);
  __syncthreads();
  G1L2(3, Y1A, Y1B);
  E2(2, Y0A, Y0B);
  __syncthreads();
  E2(3, Y1A, Y1B);

  // ---- epilogue: bias2+relu in regs, fc directly from accumulators ----
  float p0A = 0.0f, p1A = 0.0f, p0B = 0.0f, p1B = 0.0f;
#pragma unroll
  for (int ot = 0; ot < 2; ++ot) {
    int ob = (2 * w + ot) * 16 + q * 4;  // o base, 4 contiguous per lane
    float4 bv = *(const float4*)&bias2[ob];
#pragma unroll
    for (int nt = 0; nt < 2; ++nt) {
      int n = nt * 16 + l15;
      float4 w0 = *(const float4*)&fc_w[n * 128 + ob];
      float4 w1v = *(const float4*)&fc_w[4096 + n * 128 + ob];
      float hA0 = fmaxf(acc2A[ot][nt][0] + bv.x, 0.0f);
      float hA1 = fmaxf(acc2A[ot][nt][1] + bv.y, 0.0f);
      float hA2 = fmaxf(acc2A[ot][nt][2] + bv.z, 0.0f);
      float hA3 = fmaxf(acc2A[ot][nt][3] + bv.w, 0.0f);
      float hB0 = fmaxf(acc2B[ot][nt][0] + bv.x, 0.0f);
      float hB1 = fmaxf(acc2B[ot][nt][1] + bv.y, 0.0f);
      float hB2 = fmaxf(acc2B[ot][nt][2] + bv.z, 0.0f);
      float hB3 = fmaxf(acc2B[ot][nt][3] + bv.w, 0.0f);
      p0A = fmaf(hA0, w0.x, fmaf(hA1, w0.y, fmaf(hA2, w0.z, fmaf(hA3, w0.w, p0A))));
      p1A = fmaf(hA0, w1v.x, fmaf(hA1, w1v.y, fmaf(hA2, w1v.z, fmaf(hA3, w1v.w, p1A))));
      p0B = fmaf(hB0, w0.x, fmaf(hB1, w0.y, fmaf(hB2, w0.z, fmaf(hB3, w0.w, p0B))));
      p1B = fmaf(hB0, w1v.x, fmaf(hB1, w1v.y, fmaf(hB2, w1v.z, fmaf(hB3, w1v.w, p1B))));
    }
  }
#pragma unroll
  for (int off = 32; off >= 1; off >>= 1) {
    p0A += __shfl_xor(p0A, off);
    p1A += __shfl_xor(p1A, off);
    p0B += __shfl_xor(p0B, off);
    p1B += __shfl_xor(p1B, off);
  }
  if (lane == 0) {
    red[w * 4 + 0] = p0A;
    red[w * 4 + 1] = p1A;
    red[w * 4 + 2] = p0B;
    red[w * 4 + 3] = p1B;
  }
  __syncthreads();
  if (tid < 4) {
    float s = red[tid] + red[4 + tid] + red[8 + tid] + red[12 + tid] + fc_b[tid & 1];
    out[(b0 + (tid >> 1)) * 2 + (tid & 1)] = s;
  }
}

extern "C" void kernel_launch(void* const* d_in, const int* in_sizes, int n_in,
                              void* d_out, int out_size, void* d_ws, size_t ws_size,
                              hipStream_t stream) {
  const float* x        = (const float*)d_in[0];
  const float* adj      = (const float*)d_in[1];
  const float* adj_bias = (const float*)d_in[2];
  const float* w1       = (const float*)d_in[3];
  const float* b1       = (const float*)d_in[4];
  const float* w2       = (const float*)d_in[5];
  const float* b2       = (const float*)d_in[6];
  const float* fc_w     = (const float*)d_in[7];
  const float* fc_b     = (const float*)d_in[8];
  float* out = (float*)d_out;
  char* ws   = (char*)d_ws;

  prep_kernel<<<17, 256, 0, stream>>>(adj, adj_bias, w1, b1, w2, b2, ws);
  dgcnn_kernel<<<4096, 256, 0, stream>>>(x, ws, fc_w, fc_b, out);
}

// Round 13
// 201.331 us; speedup vs baseline: 2.0945x; 1.0305x over previous
//
#include <hip/hip_runtime.h>

typedef unsigned short u16;
typedef unsigned int u32;
typedef short bf16x8 __attribute__((ext_vector_type(8)));
typedef float f32x4 __attribute__((ext_vector_type(4)));

#define MFMA16(a, b, c) __builtin_amdgcn_mfma_f32_16x16x32_bf16((a), (b), (c), 0, 0, 0)

__device__ __forceinline__ u16 f2bf(float f) {
  u32 u = __builtin_bit_cast(u32, f);
  u += 0x7FFFu + ((u >> 16) & 1u);
  return (u16)(u >> 16);
}
// packed f32x2 -> bf16x2; HW builtin when available, software RNE otherwise
__device__ __forceinline__ u32 pk2bf(float a, float b) {
#if __has_builtin(__builtin_amdgcn_cvt_pk_bf16_f32)
  auto v = __builtin_amdgcn_cvt_pk_bf16_f32(a, b);
  return __builtin_bit_cast(u32, v);
#else
  return (u32)f2bf(a) | ((u32)f2bf(b) << 16);
#endif
}

// ws byte offsets (prep layouts identical to R8 -- verified)
#define WS_MGF   0         // bf16 [8 jt][64 lane][8 j]      B-frags of M^T   (8192 B)
#define WS_WT1F  8192      // bf16 [8 ot][2 h][4 ks][64][8]  B-frags of Wp1   (65536 B)
#define WS_WT2F  73728     // bf16 [8 mt][4 h][4 ks][64][8]  A-frags of Wp2^T (131072 B)
#define WS_B1    204800    // f32 [128]  bias1 + T0-fold
#define WS_B2    205312    // f32 [128]  bias2 + T0-fold

__global__ void prep_kernel(const float* __restrict__ adj,
                            const float* __restrict__ adj_bias,
                            const float* __restrict__ w1,
                            const float* __restrict__ b1,
                            const float* __restrict__ w2,
                            const float* __restrict__ b2,
                            char* __restrict__ ws) {
  const int tid = threadIdx.x;
  if (blockIdx.x == 0) {
    __shared__ float sa[1024], Ls[1024], L2s[1024], L3s[1024], sdre[32];
    float bias = adj_bias[0];
    for (int i = tid; i < 1024; i += 256) sa[i] = fmaxf(adj[i] + bias, 0.0f);
    __syncthreads();
    if (tid < 32) {
      float s = 0.0f;
      for (int c = 0; c < 32; ++c) s += sa[tid * 32 + c];
      sdre[tid] = 1.0f / sqrtf(s + 1e-5f);
    }
    __syncthreads();
    for (int i = tid; i < 1024; i += 256) {
      int n = i >> 5, c = i & 31;
      Ls[i] = (n == c ? 1.0f : 0.0f) - sdre[n] * sa[i] * sdre[c];
    }
    __syncthreads();
    for (int i = tid; i < 1024; i += 256) {
      int r = i >> 5, c = i & 31;
      float s = 0.0f;
      for (int m = 0; m < 32; ++m) s += Ls[r * 32 + m] * Ls[m * 32 + c];
      L2s[i] = s;
    }
    __syncthreads();
    for (int i = tid; i < 1024; i += 256) {
      int r = i >> 5, c = i & 31;
      float s = 0.0f;
      for (int m = 0; m < 32; ++m) s += L2s[r * 32 + m] * Ls[m * 32 + c];
      L3s[i] = s;
    }
    __syncthreads();
    // M stacked [128x32]: rows 0-31 I, 32-63 L, 64-95 2L^2-I, 96-127 4L^3-3L.
    // B-fragments of M^T: MGf[jt][lane][j] = M[col=jt*16+(lane&15)][k=(lane>>4)*8+j]
    u16* MGf = (u16*)(ws + WS_MGF);
    for (int i = tid; i < 4096; i += 256) {
      int jt = i >> 9, lane = (i >> 3) & 63, j = i & 7;
      int col = jt * 16 + (lane & 15);
      int k = ((lane >> 4) << 3) + j;
      int kk = col >> 5, np = col & 31;
      float v;
      if (kk == 0)      v = (np == k) ? 1.0f : 0.0f;
      else if (kk == 1) v = Ls[np * 32 + k];
      else if (kk == 2) v = 2.0f * L2s[np * 32 + k] - (np == k ? 1.0f : 0.0f);
      else              v = 4.0f * L3s[np * 32 + k] - 3.0f * Ls[np * 32 + k];
      MGf[i] = f2bf(v);
    }
    float* B1 = (float*)(ws + WS_B1);
    float* B2 = (float*)(ws + WS_B2);
    if (tid < 128) {
      float s = b1[tid];
      for (int c = 0; c < 60; ++c) s += w1[(c * 5) * 128 + tid];
      B1[tid] = s;
    } else {
      int o = tid - 128;
      float s = b2[o];
      for (int c = 0; c < 128; ++c) s += w2[(c * 5) * 128 + o];
      B2[o] = s;
    }
  } else {
    u16* WT1F = (u16*)(ws + WS_WT1F);
    u16* WT2F = (u16*)(ws + WS_WT2F);
    int g = (blockIdx.x - 1) * 256 + tid;
    // WT1F bits: j[0:3) lane[3:9) ks[9:11) h[11:12) ot[12:15)
    // element = w1 at kterm=ks, c=h*32+q*8+j (0 if c>=60), o=ot*16+(lane&15)
    for (int i = g; i < 32768; i += 16 * 256) {
      int j = i & 7, lane = (i >> 3) & 63, ks = (i >> 9) & 3;
      int h = (i >> 11) & 1, ot = i >> 12;
      int q = lane >> 4;
      int c = h * 32 + q * 8 + j;
      int o = ot * 16 + (lane & 15);
      WT1F[i] = (c < 60) ? f2bf(w1[(c * 5 + ks + 1) * 128 + o]) : (u16)0;
    }
    // WT2F bits: j[0:3) lane[3:9) ks[9:11) h[11:13) mt[13:16)
    // element = w2 at kterm=ks, c2=h*32+q*8+j, o=mt*16+(lane&15)
    for (int i = g; i < 65536; i += 16 * 256) {
      int j = i & 7, lane = (i >> 3) & 63, ks = (i >> 9) & 3;
      int h = (i >> 11) & 3, mt = i >> 13;
      int q = lane >> 4;
      int c2 = h * 32 + q * 8 + j;
      int o = mt * 16 + (lane & 15);
      WT2F[i] = f2bf(w2[(c2 * 5 + ks + 1) * 128 + o]);
    }
  }
}

// R8 structure (256 thr / 4 waves / chunked-K / aligned strides 40/36/136)
// generalized to FOUR batches per block: weight frags, mB, and fc_w amortize
// over 4 batches (~70 KB global/batch vs R8's ~125); barriers and prologue
// per batch halve; each phase has 4 independent batch chains (ILP).
// LDS 70 KB -> 2 blocks/CU.
__global__ __launch_bounds__(256, 2) void dgcnn_kernel(
    const float* __restrict__ x,
    const char* __restrict__ ws,
    const float* __restrict__ fc_w,
    const float* __restrict__ fc_b,
    float* __restrict__ out) {
  __shared__ __align__(16) char arena[71680];
  __shared__ float red[32];
  u16* Xt[4];
  u16* Ht[4];
  u16* Y[4];
#pragma unroll
  for (int bb = 0; bb < 4; ++bb) {
    Xt[bb] = (u16*)(arena + bb * 5120);           // [64 c][40] each
    Ht[bb] = (u16*)(arena + bb * 9216);           // [128 o][36] (overlays Xt)
    Y[bb]  = (u16*)(arena + 36864 + bb * 8704);   // [32 np][136]
  }

  const u16* MGf  = (const u16*)(ws + WS_MGF);
  const u16* WT1F = (const u16*)(ws + WS_WT1F);
  const u16* WT2F = (const u16*)(ws + WS_WT2F);
  const float* bias1 = (const float*)(ws + WS_B1);
  const float* bias2 = (const float*)(ws + WS_B2);

  const int tid = threadIdx.x;
  const int w = tid >> 6, lane = tid & 63;
  const int l15 = lane & 15, q = lane >> 4;
  const int b0 = blockIdx.x * 4;
  const f32x4 z4 = {0.0f, 0.0f, 0.0f, 0.0f};

  // M^T B-fragments: wave w covers M^T col tiles 2w, 2w+1 (k-term = w)
  bf16x8 mB0 = *(const bf16x8*)(MGf + ((2 * w + 0) * 64 + lane) * 8);
  bf16x8 mB1 = *(const bf16x8*)(MGf + ((2 * w + 1) * 64 + lane) * 8);

  // ---- stage x^T (4 batches); rows 60..63 zeroed ----
  for (int i = tid; i < 160; i += 256) {
    int r = 60 + i / 40, c = i % 40;
#pragma unroll
    for (int bb = 0; bb < 4; ++bb) Xt[bb][r * 40 + c] = 0;
  }
  const float* xb = x + (size_t)b0 * 1920;
  for (int i = tid; i < 1920; i += 256) {
    int n = i / 60, c = i - n * 60;
    u32 p01 = pk2bf(xb[i], xb[1920 + i]);
    u32 p23 = pk2bf(xb[3840 + i], xb[5760 + i]);
    Xt[0][c * 40 + n] = (u16)p01;
    Xt[1][c * 40 + n] = (u16)(p01 >> 16);
    Xt[2][c * 40 + n] = (u16)p23;
    Xt[3][c * 40 + n] = (u16)(p23 >> 16);
  }
  __syncthreads();

  // ---------------- layer 1: 2 kc-chunks, acc carried in regs ----------------
  f32x4 acc1[4][2][2];  // [batch][nt][ot]
#pragma unroll
  for (int bb = 0; bb < 4; ++bb)
#pragma unroll
    for (int i = 0; i < 2; ++i)
#pragma unroll
      for (int j = 0; j < 2; ++j) acc1[bb][i][j] = z4;

#pragma unroll
  for (int h = 0; h < 2; ++h) {
    // G1: Y[np][w*32 + c_local] = T~[kterm=w][np][c = 32h + c_local]
#pragma unroll
    for (int bb = 0; bb < 4; ++bb) {
      f32x4 g[2][2];
#pragma unroll
      for (int mtl = 0; mtl < 2; ++mtl) {
        int roff = ((2 * h + mtl) * 16 + l15) * 40 + q * 8;
        bf16x8 aX = *(const bf16x8*)&Xt[bb][roff];
        g[mtl][0] = MFMA16(aX, mB0, z4);
        g[mtl][1] = MFMA16(aX, mB1, z4);
      }
#pragma unroll
      for (int mtl = 0; mtl < 2; ++mtl)
#pragma unroll
        for (int jtl = 0; jtl < 2; ++jtl) {
          int np = jtl * 16 + l15;
          int off = np * 136 + w * 32 + mtl * 16 + q * 4;
          uint2 v;
          v.x = pk2bf(g[mtl][jtl][0], g[mtl][jtl][1]);
          v.y = pk2bf(g[mtl][jtl][2], g[mtl][jtl][3]);
          *(uint2*)&Y[bb][off] = v;
        }
    }
    __syncthreads();
    // einsum1 partial over this chunk's 128 kc (weights shared by 4 batches)
#pragma unroll
    for (int ks = 0; ks < 4; ++ks) {
      bf16x8 wfa = *(const bf16x8*)(WT1F + ((((2 * w + 0) * 2 + h) * 4 + ks) * 64 + lane) * 8);
      bf16x8 wfb = *(const bf16x8*)(WT1F + ((((2 * w + 1) * 2 + h) * 4 + ks) * 64 + lane) * 8);
      int yoff = ks * 32 + q * 8;
#pragma unroll
      for (int bb = 0; bb < 4; ++bb) {
        bf16x8 a0 = *(const bf16x8*)&Y[bb][l15 * 136 + yoff];
        bf16x8 a1 = *(const bf16x8*)&Y[bb][(16 + l15) * 136 + yoff];
        acc1[bb][0][0] = MFMA16(a0, wfa, acc1[bb][0][0]);
        acc1[bb][0][1] = MFMA16(a0, wfb, acc1[bb][0][1]);
        acc1[bb][1][0] = MFMA16(a1, wfa, acc1[bb][1][0]);
        acc1[bb][1][1] = MFMA16(a1, wfb, acc1[bb][1][1]);
      }
    }
    if (h == 0) __syncthreads();  // next G1 rewrites Y
  }
  // bias+relu -> Ht (Xt dead: all Xt reads preceded the last post-G1 barrier)
#pragma unroll
  for (int ot = 0; ot < 2; ++ot) {
    int o = (2 * w + ot) * 16 + l15;
    float bv = bias1[o];
#pragma unroll
    for (int mt = 0; mt < 2; ++mt) {
      int off = o * 36 + mt * 16 + q * 4;
#pragma unroll
      for (int bb = 0; bb < 4; ++bb) {
        uint2 v;
        v.x = pk2bf(fmaxf(acc1[bb][mt][ot][0] + bv, 0.0f), fmaxf(acc1[bb][mt][ot][1] + bv, 0.0f));
        v.y = pk2bf(fmaxf(acc1[bb][mt][ot][2] + bv, 0.0f), fmaxf(acc1[bb][mt][ot][3] + bv, 0.0f));
        *(uint2*)&Ht[bb][off] = v;
      }
    }
  }
  __syncthreads();

  // ---------------- layer 2: 4 kc-chunks, acc carried in regs ----------------
  f32x4 acc2[4][2][2];  // [batch][ot][nt]
#pragma unroll
  for (int bb = 0; bb < 4; ++bb)
#pragma unroll
    for (int i = 0; i < 2; ++i)
#pragma unroll
      for (int j = 0; j < 2; ++j) acc2[bb][i][j] = z4;

#pragma unroll
  for (int h = 0; h < 4; ++h) {
    // G1: Y[np][w*32 + c2_local] = T~2[kterm=w][np][o = 32h + c2_local]
#pragma unroll
    for (int bb = 0; bb < 4; ++bb) {
      f32x4 g[2][2];
#pragma unroll
      for (int mtl = 0; mtl < 2; ++mtl) {
        int roff = ((2 * h + mtl) * 16 + l15) * 36 + q * 8;
        bf16x8 aH = *(const bf16x8*)&Ht[bb][roff];
        g[mtl][0] = MFMA16(aH, mB0, z4);
        g[mtl][1] = MFMA16(aH, mB1, z4);
      }
#pragma unroll
      for (int mtl = 0; mtl < 2; ++mtl)
#pragma unroll
        for (int jtl = 0; jtl < 2; ++jtl) {
          int np = jtl * 16 + l15;
          int off = np * 136 + w * 32 + mtl * 16 + q * 4;
          uint2 v;
          v.x = pk2bf(g[mtl][jtl][0], g[mtl][jtl][1]);
          v.y = pk2bf(g[mtl][jtl][2], g[mtl][jtl][3]);
          *(uint2*)&Y[bb][off] = v;
        }
    }
    __syncthreads();
    // einsum2 partial (flipped): D[o][n] += Wp2^T[o][chunk kc] @ Y^T[kc][n]
#pragma unroll
    for (int ks = 0; ks < 4; ++ks) {
      bf16x8 wfa = *(const bf16x8*)(WT2F + ((((2 * w + 0) * 4 + h) * 4 + ks) * 64 + lane) * 8);
      bf16x8 wfb = *(const bf16x8*)(WT2F + ((((2 * w + 1) * 4 + h) * 4 + ks) * 64 + lane) * 8);
      int yoff = ks * 32 + q * 8;
#pragma unroll
      for (int bb = 0; bb < 4; ++bb) {
        bf16x8 by0 = *(const bf16x8*)&Y[bb][l15 * 136 + yoff];
        bf16x8 by1 = *(const bf16x8*)&Y[bb][(16 + l15) * 136 + yoff];
        acc2[bb][0][0] = MFMA16(wfa, by0, acc2[bb][0][0]);
        acc2[bb][0][1] = MFMA16(wfa, by1, acc2[bb][0][1]);
        acc2[bb][1][0] = MFMA16(wfb, by0, acc2[bb][1][0]);
        acc2[bb][1][1] = MFMA16(wfb, by1, acc2[bb][1][1]);
      }
    }
    if (h < 3) __syncthreads();  // next G1 rewrites Y
  }

  // ---- epilogue: bias2+relu in regs, fc directly from accumulators ----
  float p0[4] = {0, 0, 0, 0}, p1[4] = {0, 0, 0, 0};
#pragma unroll
  for (int ot = 0; ot < 2; ++ot) {
    int ob = (2 * w + ot) * 16 + q * 4;  // o base, 4 contiguous per lane
    float4 bv = *(const float4*)&bias2[ob];
#pragma unroll
    for (int nt = 0; nt < 2; ++nt) {
      int n = nt * 16 + l15;
      float4 w0 = *(const float4*)&fc_w[n * 128 + ob];
      float4 w1v = *(const float4*)&fc_w[4096 + n * 128 + ob];
#pragma unroll
      for (int bb = 0; bb < 4; ++bb) {
        float h0 = fmaxf(acc2[bb][ot][nt][0] + bv.x, 0.0f);
        float h1 = fmaxf(acc2[bb][ot][nt][1] + bv.y, 0.0f);
        float h2 = fmaxf(acc2[bb][ot][nt][2] + bv.z, 0.0f);
        float h3 = fmaxf(acc2[bb][ot][nt][3] + bv.w, 0.0f);
        p0[bb] = fmaf(h0, w0.x, fmaf(h1, w0.y, fmaf(h2, w0.z, fmaf(h3, w0.w, p0[bb]))));
        p1[bb] = fmaf(h0, w1v.x, fmaf(h1, w1v.y, fmaf(h2, w1v.z, fmaf(h3, w1v.w, p1[bb]))));
      }
    }
  }
#pragma unroll
  for (int off = 32; off >= 1; off >>= 1) {
#pragma unroll
    for (int bb = 0; bb < 4; ++bb) {
      p0[bb] += __shfl_xor(p0[bb], off);
      p1[bb] += __shfl_xor(p1[bb], off);
    }
  }
  if (lane == 0) {
#pragma unroll
    for (int bb = 0; bb < 4; ++bb) {
      red[w * 8 + bb * 2 + 0] = p0[bb];
      red[w * 8 + bb * 2 + 1] = p1[bb];
    }
  }
  __syncthreads();
  if (tid < 8) {
    float s = red[tid] + red[8 + tid] + red[16 + tid] + red[24 + tid] + fc_b[tid & 1];
    out[(b0 + (tid >> 1)) * 2 + (tid & 1)] = s;
  }
}

extern "C" void kernel_launch(void* const* d_in, const int* in_sizes, int n_in,
                              void* d_out, int out_size, void* d_ws, size_t ws_size,
                              hipStream_t stream) {
  const float* x        = (const float*)d_in[0];
  const float* adj      = (const float*)d_in[1];
  const float* adj_bias = (const float*)d_in[2];
  const float* w1       = (const float*)d_in[3];
  const float* b1       = (const float*)d_in[4];
  const float* w2       = (const float*)d_in[5];
  const float* b2       = (const float*)d_in[6];
  const float* fc_w     = (const float*)d_in[7];
  const float* fc_b     = (const float*)d_in[8];
  float* out = (float*)d_out;
  char* ws   = (char*)d_ws;

  prep_kernel<<<17, 256, 0, stream>>>(adj, adj_bias, w1, b1, w2, b2, ws);
  dgcnn_kernel<<<2048, 256, 0, stream>>>(x, ws, fc_w, fc_b, out);
}